// Round 14
// baseline (1332.997 us; speedup 1.0000x reference)
//
#include <hip/hip_runtime.h>

#define UN 100000
#define INN 50000
#define UIN 150000
#define DN 64
#define KK 192
#define TILE 32
#define LPAD 200  // ushort cols per LDS row: 400B stride, 16B-aligned, <=2-way banks
#define NROWS_ALL (UIN + UN)

typedef __attribute__((ext_vector_type(8))) short bf16x8;
typedef __attribute__((ext_vector_type(4))) float f32x4;

// mish(x) = x * (t^2 + 2t) / (t^2 + 2t + 2), t = e^x
__device__ __forceinline__ float mish_f(float x) {
  float t = __expf(x);
  float num = fmaf(t, t, 2.0f * t);
  float m = x * num / (num + 2.0f);
  return (x > 20.0f) ? x : m;
}

__device__ __forceinline__ float bf2f(ushort u) {
  return __uint_as_float(((unsigned int)u) << 16);
}
__device__ __forceinline__ ushort f2bf(float f) {  // RNE
  unsigned int u = __float_as_uint(f);
  u += 0x7FFFu + ((u >> 16) & 1u);
  return (ushort)(u >> 16);
}

__global__ void init_kernel(const float* __restrict__ ue, const float* __restrict__ ie,
                            ushort* __restrict__ egoh, float* __restrict__ outacc) {
  size_t i = (size_t)blockIdx.x * blockDim.x + threadIdx.x;
  size_t total = (size_t)UIN * DN;
  if (i >= total) return;
  size_t usz = (size_t)UN * DN;
  float v = (i < usz) ? ue[i] : ie[i - usz];
  egoh[i] = f2bf(v);
  outacc[i] = v;
}

__global__ void convert_w(const float* __restrict__ W, ushort* __restrict__ Wb, int n) {
  int i = blockIdx.x * blockDim.x + threadIdx.x;
  if (i < n) Wb[i] = f2bf(W[i]);
}

// ---------------- CSR build: combined A(+0) and S(+UIN) rows, lists padded to x4 ----------------
__global__ void hist_kernel(const int* __restrict__ rows, int* __restrict__ cnt, int nnz) {
  int e = blockIdx.x * blockDim.x + threadIdx.x;
  if (e < nnz) atomicAdd(&cnt[rows[e]], 1);
}

// level 0: per-block (256) inclusive scan of padded counts -> exclusive offsets + block sums
__global__ __launch_bounds__(256) void scan1(const int* __restrict__ cnt,
                                             int* __restrict__ rowptr,
                                             int* __restrict__ bsum, int n) {
  __shared__ int sh[256];
  int i = blockIdx.x * 256 + threadIdx.x;
  int v = (i < n) ? ((cnt[i] + 3) & ~3) : 0;
  sh[threadIdx.x] = v;
  __syncthreads();
  #pragma unroll
  for (int off = 1; off < 256; off <<= 1) {
    int t = (threadIdx.x >= off) ? sh[threadIdx.x - off] : 0;
    __syncthreads();
    sh[threadIdx.x] += t;
    __syncthreads();
  }
  if (i < n) rowptr[i] = sh[threadIdx.x] - v;
  if (threadIdx.x == 255) bsum[blockIdx.x] = sh[255];
}

// level 1: single-block scan of block sums (nb <= 1024)
__global__ __launch_bounds__(1024) void scan2(int* __restrict__ bsum, int nb) {
  __shared__ int sh[1024];
  int tid = threadIdx.x;
  int v = (tid < nb) ? bsum[tid] : 0;
  sh[tid] = v;
  __syncthreads();
  #pragma unroll
  for (int off = 1; off < 1024; off <<= 1) {
    int t = (tid >= off) ? sh[tid - off] : 0;
    __syncthreads();
    sh[tid] += t;
    __syncthreads();
  }
  if (tid < nb) bsum[tid] = sh[tid] - v;  // exclusive
}

// level 2: add block offsets; produce rowptr + scatter cursors + final total
__global__ void scan3(int* __restrict__ rowptr, const int* __restrict__ bsum,
                      const int* __restrict__ cnt, int* __restrict__ tmp, int n) {
  int i = blockIdx.x * 256 + threadIdx.x;
  if (i >= n) return;
  int r = rowptr[i] + bsum[i >> 8];
  rowptr[i] = r;
  tmp[i] = r;
  if (i == n - 1) rowptr[n] = r + ((cnt[i] + 3) & ~3);
}

__global__ void scatter_kernel(const int* __restrict__ rows, const int* __restrict__ cols,
                               const float* __restrict__ vals, int* __restrict__ tmp,
                               int2* __restrict__ packed, int nnz) {
  int e = blockIdx.x * blockDim.x + threadIdx.x;
  if (e >= nnz) return;
  int pos = atomicAdd(&tmp[rows[e]], 1);
  packed[pos] = make_int2(cols[e], __float_as_int(vals[e]));
}

// ---------------- SpMM: wave = 1 row, 16 lanes/row-slice, 4 edge slots, 4-deep ILP ----------------
__global__ __launch_bounds__(256) void spmm4(const int* __restrict__ rowptr,
                                             const int2* __restrict__ packed,
                                             const ushort* __restrict__ xh,
                                             float* __restrict__ out, int nrows) {
  int r = blockIdx.x * 4 + (threadIdx.x >> 6);
  if (r >= nrows) return;
  int l = threadIdx.x & 63;
  int sub = l >> 4;        // edge slot 0..3
  int c16 = l & 15;        // feature group (4 bf16)
  int beg = rowptr[r], end = rowptr[r + 1];  // count multiple of 4 (padded, val=0)
  float4 A0 = make_float4(0.f, 0.f, 0.f, 0.f);
  float4 A1 = make_float4(0.f, 0.f, 0.f, 0.f);
  float4 A2 = make_float4(0.f, 0.f, 0.f, 0.f);
  float4 A3 = make_float4(0.f, 0.f, 0.f, 0.f);
  int e = beg + sub;
  for (; e + 12 < end; e += 16) {
    int2 p0 = packed[e];
    int2 p1 = packed[e + 4];
    int2 p2 = packed[e + 8];
    int2 p3 = packed[e + 12];
    ushort4 x0 = *(const ushort4*)(xh + (((size_t)p0.x) << 6) + (c16 << 2));
    ushort4 x1 = *(const ushort4*)(xh + (((size_t)p1.x) << 6) + (c16 << 2));
    ushort4 x2 = *(const ushort4*)(xh + (((size_t)p2.x) << 6) + (c16 << 2));
    ushort4 x3 = *(const ushort4*)(xh + (((size_t)p3.x) << 6) + (c16 << 2));
    float v0 = __int_as_float(p0.y);
    float v1 = __int_as_float(p1.y);
    float v2 = __int_as_float(p2.y);
    float v3 = __int_as_float(p3.y);
    A0.x = fmaf(v0, bf2f(x0.x), A0.x); A0.y = fmaf(v0, bf2f(x0.y), A0.y);
    A0.z = fmaf(v0, bf2f(x0.z), A0.z); A0.w = fmaf(v0, bf2f(x0.w), A0.w);
    A1.x = fmaf(v1, bf2f(x1.x), A1.x); A1.y = fmaf(v1, bf2f(x1.y), A1.y);
    A1.z = fmaf(v1, bf2f(x1.z), A1.z); A1.w = fmaf(v1, bf2f(x1.w), A1.w);
    A2.x = fmaf(v2, bf2f(x2.x), A2.x); A2.y = fmaf(v2, bf2f(x2.y), A2.y);
    A2.z = fmaf(v2, bf2f(x2.z), A2.z); A2.w = fmaf(v2, bf2f(x2.w), A2.w);
    A3.x = fmaf(v3, bf2f(x3.x), A3.x); A3.y = fmaf(v3, bf2f(x3.y), A3.y);
    A3.z = fmaf(v3, bf2f(x3.z), A3.z); A3.w = fmaf(v3, bf2f(x3.w), A3.w);
  }
  for (; e < end; e += 4) {
    int2 p = packed[e];
    ushort4 xv = *(const ushort4*)(xh + (((size_t)p.x) << 6) + (c16 << 2));
    float v = __int_as_float(p.y);
    A0.x = fmaf(v, bf2f(xv.x), A0.x); A0.y = fmaf(v, bf2f(xv.y), A0.y);
    A0.z = fmaf(v, bf2f(xv.z), A0.z); A0.w = fmaf(v, bf2f(xv.w), A0.w);
  }
  A0.x += A1.x + A2.x + A3.x;
  A0.y += A1.y + A2.y + A3.y;
  A0.z += A1.z + A2.z + A3.z;
  A0.w += A1.w + A2.w + A3.w;
  A0.x += __shfl_xor(A0.x, 16); A0.y += __shfl_xor(A0.y, 16);
  A0.z += __shfl_xor(A0.z, 16); A0.w += __shfl_xor(A0.w, 16);
  A0.x += __shfl_xor(A0.x, 32); A0.y += __shfl_xor(A0.y, 32);
  A0.z += __shfl_xor(A0.z, 32); A0.w += __shfl_xor(A0.w, 32);
  if (sub == 0) *(float4*)(out + (((size_t)r) << 6) + (c16 << 2)) = A0;
}

// ---------------- Fused 3-GEMM MLP via MFMA, 256 threads, 32-row tile ----------------
// Wave w owns both 16-row halves and a 48-col N-quarter; weight B-fragments are
// double-buffered (issue kt+1's 3 loads BEFORE kt's 6 MFMAs) to hide L2 latency.
// mfma_f32_16x16x32_bf16: A lane l: row=l&15, k=(l>>4)*8+r ; B lane l: col=l&15, k=(l>>4)*8+r
// D lane l: col=l&15, row=(l>>4)*4+reg  [m89/m91 verified]
__global__ __launch_bounds__(256, 4) void fusion_mfma(
    const float* __restrict__ aout, const float* __restrict__ sout,
    const ushort* __restrict__ Wb1, const float* __restrict__ b1,
    const ushort* __restrict__ Wb2, const float* __restrict__ b2,
    const ushort* __restrict__ Wb3, const float* __restrict__ b3,
    float* __restrict__ t3out, float* __restrict__ sumsq) {
  __shared__ ushort bufA[TILE][LPAD];  // cat, later t2
  __shared__ ushort bufB[TILE][LPAD];  // t1
  __shared__ float ssred[4];
  const int tid = threadIdx.x;
  const int w = tid >> 6;      // wave 0..3 = N-quarter
  const int l = tid & 63;
  const int lg = l >> 4;       // lane group 0..3
  const int lr = l & 15;
  const int koff = lg * 8;
  const int r0 = blockIdx.x * TILE;  // UN = 3125*32

  // ---- stage cat = [u, s, u*s] as bf16, row-major [32][192] ----
  {
    int row = tid >> 3;
    int c0 = (tid & 7) * 8;
    const float4* ap = (const float4*)(aout + (((size_t)(r0 + row)) << 6) + c0);
    const float4* sp = (const float4*)(sout + (((size_t)(r0 + row)) << 6) + c0);
    float4 u0 = ap[0], u1 = ap[1];
    float4 s0 = sp[0], s1 = sp[1];
    float uu[8] = {u0.x, u0.y, u0.z, u0.w, u1.x, u1.y, u1.z, u1.w};
    float ssv[8] = {s0.x, s0.y, s0.z, s0.w, s1.x, s1.y, s1.z, s1.w};
    bf16x8 vu, vs, vm;
    #pragma unroll
    for (int j = 0; j < 8; ++j) {
      vu[j] = (short)f2bf(uu[j]);
      vs[j] = (short)f2bf(ssv[j]);
      vm[j] = (short)f2bf(uu[j] * ssv[j]);
    }
    *(bf16x8*)&bufA[row][c0] = vu;
    *(bf16x8*)&bufA[row][64 + c0] = vs;
    *(bf16x8*)&bufA[row][128 + c0] = vm;
  }
  __syncthreads();

  int n0 = (3 * w + 0) * 16 + lr;
  int n1 = (3 * w + 1) * 16 + lr;
  int n2 = (3 * w + 2) * 16 + lr;
  f32x4 acc[2][3];

  // ---- GEMM1: t1 = mish(cat @ W1^T + b1) -> bufB ----
  #pragma unroll
  for (int mt = 0; mt < 2; ++mt)
    #pragma unroll
    for (int t = 0; t < 3; ++t) acc[mt][t] = (f32x4){0.f, 0.f, 0.f, 0.f};
  {
    bf16x8 bw[2][3];
    bw[0][0] = *(const bf16x8*)(Wb1 + (size_t)n0 * KK + koff);
    bw[0][1] = *(const bf16x8*)(Wb1 + (size_t)n1 * KK + koff);
    bw[0][2] = *(const bf16x8*)(Wb1 + (size_t)n2 * KK + koff);
    #pragma unroll
    for (int kt = 0; kt < 6; ++kt) {
      const int cur = kt & 1, nxt = cur ^ 1;
      if (kt < 5) {
        bw[nxt][0] = *(const bf16x8*)(Wb1 + (size_t)n0 * KK + koff + (kt + 1) * 32);
        bw[nxt][1] = *(const bf16x8*)(Wb1 + (size_t)n1 * KK + koff + (kt + 1) * 32);
        bw[nxt][2] = *(const bf16x8*)(Wb1 + (size_t)n2 * KK + koff + (kt + 1) * 32);
      }
      bf16x8 a0 = *(const bf16x8*)&bufA[lr][koff + kt * 32];
      bf16x8 a1 = *(const bf16x8*)&bufA[16 + lr][koff + kt * 32];
      #pragma unroll
      for (int t = 0; t < 3; ++t) {
        acc[0][t] = __builtin_amdgcn_mfma_f32_16x16x32_bf16(a0, bw[cur][t], acc[0][t], 0, 0, 0);
        acc[1][t] = __builtin_amdgcn_mfma_f32_16x16x32_bf16(a1, bw[cur][t], acc[1][t], 0, 0, 0);
      }
    }
  }
  {
    float bias0 = b1[n0], bias1 = b1[n1], bias2 = b1[n2];
    float bias[3] = {bias0, bias1, bias2};
    int nn[3] = {n0, n1, n2};
    #pragma unroll
    for (int t = 0; t < 3; ++t) {
      #pragma unroll
      for (int mt = 0; mt < 2; ++mt) {
        int rowb = (mt << 4) + (lg << 2);
        #pragma unroll
        for (int q = 0; q < 4; ++q)
          bufB[rowb + q][nn[t]] = f2bf(mish_f(acc[mt][t][q] + bias[t]));
      }
    }
  }
  __syncthreads();

  // ---- GEMM2: t2 = mish(t1 @ W2^T + b2) -> bufA ----
  #pragma unroll
  for (int mt = 0; mt < 2; ++mt)
    #pragma unroll
    for (int t = 0; t < 3; ++t) acc[mt][t] = (f32x4){0.f, 0.f, 0.f, 0.f};
  {
    bf16x8 bw[2][3];
    bw[0][0] = *(const bf16x8*)(Wb2 + (size_t)n0 * KK + koff);
    bw[0][1] = *(const bf16x8*)(Wb2 + (size_t)n1 * KK + koff);
    bw[0][2] = *(const bf16x8*)(Wb2 + (size_t)n2 * KK + koff);
    #pragma unroll
    for (int kt = 0; kt < 6; ++kt) {
      const int cur = kt & 1, nxt = cur ^ 1;
      if (kt < 5) {
        bw[nxt][0] = *(const bf16x8*)(Wb2 + (size_t)n0 * KK + koff + (kt + 1) * 32);
        bw[nxt][1] = *(const bf16x8*)(Wb2 + (size_t)n1 * KK + koff + (kt + 1) * 32);
        bw[nxt][2] = *(const bf16x8*)(Wb2 + (size_t)n2 * KK + koff + (kt + 1) * 32);
      }
      bf16x8 a0 = *(const bf16x8*)&bufB[lr][koff + kt * 32];
      bf16x8 a1 = *(const bf16x8*)&bufB[16 + lr][koff + kt * 32];
      #pragma unroll
      for (int t = 0; t < 3; ++t) {
        acc[0][t] = __builtin_amdgcn_mfma_f32_16x16x32_bf16(a0, bw[cur][t], acc[0][t], 0, 0, 0);
        acc[1][t] = __builtin_amdgcn_mfma_f32_16x16x32_bf16(a1, bw[cur][t], acc[1][t], 0, 0, 0);
      }
    }
  }
  __syncthreads();  // all bufA reads (GEMM1 kt loop) are before the previous barrier; this one orders bufB reads vs bufA writes below
  {
    float bias0 = b2[n0], bias1 = b2[n1], bias2 = b2[n2];
    float bias[3] = {bias0, bias1, bias2};
    int nn[3] = {n0, n1, n2};
    #pragma unroll
    for (int t = 0; t < 3; ++t) {
      #pragma unroll
      for (int mt = 0; mt < 2; ++mt) {
        int rowb = (mt << 4) + (lg << 2);
        #pragma unroll
        for (int q = 0; q < 4; ++q)
          bufA[rowb + q][nn[t]] = f2bf(mish_f(acc[mt][t][q] + bias[t]));
      }
    }
  }
  __syncthreads();

  // ---- GEMM3: t3 = t2 @ W3^T + b3 -> global + sumsq; wave w = 16-col tile w ----
  f32x4 a3[2];
  a3[0] = (f32x4){0.f, 0.f, 0.f, 0.f};
  a3[1] = (f32x4){0.f, 0.f, 0.f, 0.f};
  const int n3 = w * 16 + lr;
  {
    bf16x8 bw[2];
    bw[0] = *(const bf16x8*)(Wb3 + (size_t)n3 * KK + koff);
    #pragma unroll
    for (int kt = 0; kt < 6; ++kt) {
      const int cur = kt & 1, nxt = cur ^ 1;
      if (kt < 5)
        bw[nxt] = *(const bf16x8*)(Wb3 + (size_t)n3 * KK + koff + (kt + 1) * 32);
      bf16x8 a0 = *(const bf16x8*)&bufA[lr][koff + kt * 32];
      bf16x8 a1 = *(const bf16x8*)&bufA[16 + lr][koff + kt * 32];
      a3[0] = __builtin_amdgcn_mfma_f32_16x16x32_bf16(a0, bw[cur], a3[0], 0, 0, 0);
      a3[1] = __builtin_amdgcn_mfma_f32_16x16x32_bf16(a1, bw[cur], a3[1], 0, 0, 0);
    }
  }
  float b3v = b3[n3];
  float lss = 0.f;
  #pragma unroll
  for (int mt = 0; mt < 2; ++mt) {
    int rowb = r0 + (mt << 4) + (lg << 2);
    #pragma unroll
    for (int q = 0; q < 4; ++q) {
      float v = a3[mt][q] + b3v;
      t3out[(((size_t)(rowb + q)) << 6) + n3] = v;
      lss = fmaf(v, v, lss);
    }
  }
  #pragma unroll
  for (int off = 32; off > 0; off >>= 1) lss += __shfl_down(lss, off);
  if (l == 0) ssred[w] = lss;
  __syncthreads();
  if (tid == 0) atomicAdd(sumsq, ssred[0] + ssred[1] + ssred[2] + ssred[3]);
}

__global__ void finalize_kernel(const float* __restrict__ t3, const float* __restrict__ sumsq,
                                const float* __restrict__ aout, ushort* __restrict__ egoh,
                                float* __restrict__ outacc, int last) {
  size_t i = (size_t)blockIdx.x * blockDim.x + threadIdx.x;
  size_t total = (size_t)UIN * DN;
  if (i >= total) return;
  size_t usz = (size_t)UN * DN;
  float v;
  if (i < usz) {
    float inv = 1.0f / sqrtf(sumsq[0]);
    v = t3[i] * inv;
  } else {
    v = aout[i];
  }
  if (last) {
    outacc[i] = (outacc[i] + v) * 0.25f;
  } else {
    egoh[i] = f2bf(v);
    outacc[i] += v;
  }
}

extern "C" void kernel_launch(void* const* d_in, const int* in_sizes, int n_in,
                              void* d_out, int out_size, void* d_ws, size_t ws_size,
                              hipStream_t stream) {
  const float* user_emb = (const float*)d_in[0];
  const float* item_emb = (const float*)d_in[1];
  const int* A_rows = (const int*)d_in[2];
  const int* A_cols = (const int*)d_in[3];
  const float* A_vals = (const float*)d_in[4];
  const int* S_rows = (const int*)d_in[5];
  const int* S_cols = (const int*)d_in[6];
  const float* S_vals = (const float*)d_in[7];
  const float* W1 = (const float*)d_in[8];
  const float* b1 = (const float*)d_in[9];
  const float* W2 = (const float*)d_in[10];
  const float* b2 = (const float*)d_in[11];
  const float* W3 = (const float*)d_in[12];
  const float* b3 = (const float*)d_in[13];
  const int nnzA = in_sizes[2];
  const int nnzS = in_sizes[5];

  float* ws = (float*)d_ws;
  size_t off = 0;
  ushort* egoh = (ushort*)(ws + off); off += (size_t)UIN * DN / 2;  // bf16 embeddings
  float* aout = ws + off; off += (size_t)UIN * DN;
  float* sout = ws + off; off += (size_t)UN * DN;   // aliased as t3 (per-block read-then-write)
  float* ss = ws + off;   off += 16;
  ushort* Wb1 = (ushort*)(ws + off); off += KK * KK / 2;
  ushort* Wb2 = (ushort*)(ws + off); off += KK * KK / 2;
  ushort* Wb3 = (ushort*)(ws + off); off += KK * DN / 2;
  int* cnt = (int*)(ws + off);    off += NROWS_ALL;        // A rows then S rows
  int* rowptr = (int*)(ws + off); off += NROWS_ALL + 1;    // combined
  int* tmp = (int*)(ws + off);    off += NROWS_ALL;
  int* bsum = (int*)(ws + off);   off += 1024;
  off = (off + 1) & ~(size_t)1;  // 8B align
  const size_t padAll = (size_t)nnzA + (size_t)nnzS + 4 * NROWS_ALL;
  int2* pAll = (int2*)(ws + off); off += 2 * padAll;
  float* outacc = (float*)d_out;
  float* t3 = sout;

  const size_t total = (size_t)UIN * DN;
  const int nblk_elem = (int)((total + 255) / 256);
  const int nbScan = (NROWS_ALL + 255) / 256;  // 977 <= 1024

  // CSR build (combined): hist -> hierarchical padded scan -> scatter
  hipMemsetAsync(cnt, 0, (size_t)NROWS_ALL * sizeof(int), stream);
  hipMemsetAsync(pAll, 0, padAll * sizeof(int2), stream);
  hist_kernel<<<(nnzA + 255) / 256, 256, 0, stream>>>(A_rows, cnt, nnzA);
  hist_kernel<<<(nnzS + 255) / 256, 256, 0, stream>>>(S_rows, cnt + UIN, nnzS);
  scan1<<<nbScan, 256, 0, stream>>>(cnt, rowptr, bsum, NROWS_ALL);
  scan2<<<1, 1024, 0, stream>>>(bsum, nbScan);
  scan3<<<nbScan, 256, 0, stream>>>(rowptr, bsum, cnt, tmp, NROWS_ALL);
  scatter_kernel<<<(nnzA + 255) / 256, 256, 0, stream>>>(A_rows, A_cols, A_vals, tmp, pAll, nnzA);
  scatter_kernel<<<(nnzS + 255) / 256, 256, 0, stream>>>(S_rows, S_cols, S_vals, tmp + UIN, pAll, nnzS);

  init_kernel<<<nblk_elem, 256, 0, stream>>>(user_emb, item_emb, egoh, outacc);
  convert_w<<<(KK * KK + 255) / 256, 256, 0, stream>>>(W1, Wb1, KK * KK);
  convert_w<<<(KK * KK + 255) / 256, 256, 0, stream>>>(W2, Wb2, KK * KK);
  convert_w<<<(KK * DN + 255) / 256, 256, 0, stream>>>(W3, Wb3, KK * DN);

  for (int layer = 0; layer < 3; ++layer) {
    hipMemsetAsync(ss, 0, 64, stream);
    spmm4<<<(UIN + 3) / 4, 256, 0, stream>>>(rowptr, pAll, egoh, aout, UIN);
    spmm4<<<(UN + 3) / 4, 256, 0, stream>>>(rowptr + UIN, pAll, egoh, sout, UN);
    fusion_mfma<<<UN / TILE, 256, 0, stream>>>(aout, sout, Wb1, b1, Wb2, b2, Wb3, b3, t3, ss);
    finalize_kernel<<<nblk_elem, 256, 0, stream>>>(t3, ss, aout, egoh, outacc, layer == 2);
  }
}